// Round 1
// baseline (854.303 us; speedup 1.0000x reference)
//
#include <hip/hip_runtime.h>
#include <hip/hip_bf16.h>

// OldODEFunc: B=8192, S=268, H=1024, R=8, A=256, E=4, Z=8, P=4.
// Strategy: bf16 MFMA (16x16x32) for all big GEMMs, fp32 accumulate,
// m97-style 128x128 tile with global_load_lds width-16 staging.

typedef unsigned short u16;
typedef __bf16 bf16x8 __attribute__((ext_vector_type(8)));
typedef float f32x4 __attribute__((ext_vector_type(4)));

__device__ __forceinline__ u16 f2b(float f) {
  union { float f; unsigned u; } v; v.f = f;
  unsigned r = v.u + 0x7FFFu + ((v.u >> 16) & 1u);   // RNE
  return (u16)(r >> 16);
}
__device__ __forceinline__ float b2f(u16 s) {
  union { unsigned u; float f; } v; v.u = ((unsigned)s) << 16;
  return v.f;
}

// async global->LDS, 16B per lane; lds dest = wave-uniform base + lane*16
__device__ __forceinline__ void g2l16(const u16* g, u16* l) {
  __builtin_amdgcn_global_load_lds(
      (__attribute__((address_space(1))) void*)g,
      (__attribute__((address_space(3))) void*)l, 16, 0, 0);
}

// C = A(M x K, row-major, stride lda) * B^T where B is (N x K) row-major (ldb == K).
// MODE 0: relu(acc+bias) -> bf16 out      (ldo = N)
// MODE 1: tanh(acc+bias) -> bf16 out
// MODE 2: tanh(acc+bias+resid) -> bf16 out (in-place-safe residual)
// MODE 3: acc+bias -> f32 out, cols < nreal only (ldo = nreal)
// MODE 4: acc+bias -> bf16 out
template<int MODE>
__global__ __launch_bounds__(256)
void gemm_bt(const u16* __restrict__ A, const u16* __restrict__ B,
             const float* __restrict__ bias, const u16* __restrict__ resid,
             void* __restrict__ outp, int K, int lda, int nreal, int ldo)
{
  __shared__ __align__(16) u16 As[128 * 32];
  __shared__ __align__(16) u16 Bs[128 * 32];
  const int tid  = threadIdx.x;
  const int wave = tid >> 6;
  const int lane = tid & 63;
  const int m0 = blockIdx.y << 7;
  const int n0 = blockIdx.x << 7;
  const int wr = wave >> 1, wc = wave & 1;       // 2x2 waves over 128x128
  const int lrow = lane & 15, quad = lane >> 4;  // MFMA fragment coords
  const int srow = lane >> 2, scol = (lane & 3) << 3;  // staging coords

  const u16* Ag0 = A + (size_t)(m0 + wave * 16 + srow) * lda + scol;
  const u16* Ag1 = Ag0 + (size_t)64 * lda;
  const u16* Bg0 = B + (size_t)(n0 + wave * 16 + srow) * K + scol;
  const u16* Bg1 = Bg0 + (size_t)64 * K;
  u16* Al0 = &As[wave * 512];
  u16* Al1 = &As[wave * 512 + 2048];
  u16* Bl0 = &Bs[wave * 512];
  u16* Bl1 = &Bs[wave * 512 + 2048];

  f32x4 acc[4][4];
#pragma unroll
  for (int i = 0; i < 4; i++)
#pragma unroll
    for (int j = 0; j < 4; j++) { f32x4 z = {0.f, 0.f, 0.f, 0.f}; acc[i][j] = z; }

  for (int k0 = 0; k0 < K; k0 += 32) {
    if (k0) __syncthreads();             // prior reads done before overwrite
    g2l16(Ag0 + k0, Al0);
    g2l16(Ag1 + k0, Al1);
    g2l16(Bg0 + k0, Bl0);
    g2l16(Bg1 + k0, Bl1);
    __syncthreads();                     // drains vmcnt: staging visible
    bf16x8 af[4], bfr[4];
#pragma unroll
    for (int i = 0; i < 4; i++)
      af[i] = *reinterpret_cast<const bf16x8*>(&As[(wr * 64 + i * 16 + lrow) * 32 + quad * 8]);
#pragma unroll
    for (int j = 0; j < 4; j++)
      bfr[j] = *reinterpret_cast<const bf16x8*>(&Bs[(wc * 64 + j * 16 + lrow) * 32 + quad * 8]);
#pragma unroll
    for (int i = 0; i < 4; i++)
#pragma unroll
      for (int j = 0; j < 4; j++)
        acc[i][j] = __builtin_amdgcn_mfma_f32_16x16x32_bf16(af[i], bfr[j], acc[i][j], 0, 0, 0);
  }

  // epilogue: C/D layout col = lane&15, row = quad*4 + reg
#pragma unroll
  for (int i = 0; i < 4; i++) {
    const int rowb = m0 + wr * 64 + i * 16 + quad * 4;
#pragma unroll
    for (int j = 0; j < 4; j++) {
      const int col = n0 + wc * 64 + j * 16 + lrow;
      const float bi = (col < nreal) ? bias[col] : 0.f;
#pragma unroll
      for (int r = 0; r < 4; r++) {
        const int row = rowb + r;
        float v = acc[i][j][r] + bi;
        if (MODE == 0) {
          v = v > 0.f ? v : 0.f;
          ((u16*)outp)[(size_t)row * ldo + col] = f2b(v);
        } else if (MODE == 1) {
          ((u16*)outp)[(size_t)row * ldo + col] = f2b(tanhf(v));
        } else if (MODE == 2) {
          v += b2f(resid[(size_t)row * ldo + col]);
          ((u16*)outp)[(size_t)row * ldo + col] = f2b(tanhf(v));
        } else if (MODE == 3) {
          if (col < nreal) ((float*)outp)[(size_t)row * ldo + col] = v;
        } else {
          ((u16*)outp)[(size_t)row * ldo + col] = f2b(v);
        }
      }
    }
  }
}

// res_W1 + res_W2 (8M floats each) -> bf16, vectorized float4
__global__ void conv_bulk(const float* __restrict__ w1, const float* __restrict__ w2,
                          u16* __restrict__ o1, u16* __restrict__ o2)
{
  const int n4 = (8 * 1024 * 1024) / 4;  // 2097152 float4 per tensor
  int i = blockIdx.x * 256 + threadIdx.x;
  const float* src; u16* dst;
  if (i < n4) { src = w1; dst = o1; }
  else        { i -= n4; if (i >= n4) return; src = w2; dst = o2; }
  float4 v = ((const float4*)src)[i];
  unsigned p0 = (unsigned)f2b(v.x) | ((unsigned)f2b(v.y) << 16);
  unsigned p1 = (unsigned)f2b(v.z) | ((unsigned)f2b(v.w) << 16);
  uint2 pk; pk.x = p0; pk.y = p1;
  ((uint2*)dst)[i] = pk;
}

// W0 pad(1024x288), Wf pad(384x1024), taA(256x256), taB(256x256), x_bf(8192x288)
__global__ void conv_misc(const float* __restrict__ W0, const float* __restrict__ Wf,
                          const float* __restrict__ ta_in_w, const float* __restrict__ ta_out_w,
                          const float* __restrict__ state, const float* __restrict__ t,
                          u16* __restrict__ w0_bf, u16* __restrict__ wf_bf,
                          u16* __restrict__ taA, u16* __restrict__ taB,
                          u16* __restrict__ x_bf)
{
  int i = blockIdx.x * 256 + threadIdx.x;
  const int nW0 = 1024 * 288;
  const int nWf = 384 * 1024;
  const int nTa = 256 * 256;
  const int nX  = 8192 * 288;
  if (i < nW0) {
    int o = i / 288, k = i - o * 288;
    w0_bf[i] = (k < 270) ? f2b(W0[o * 270 + k]) : (u16)0;
    return;
  }
  i -= nW0;
  if (i < nWf) {
    int n = i >> 10;
    wf_bf[i] = (n < 268) ? f2b(Wf[i]) : (u16)0;
    return;
  }
  i -= nWf;
  if (i < nTa) { taA[i] = f2b(ta_in_w[512 * 256 + i]); return; }
  i -= nTa;
  if (i < nTa) { taB[i] = f2b(ta_out_w[i]); return; }
  i -= nTa;
  if (i < nX) {
    int r = i / 288, c = i - r * 288;
    u16 v;
    if (c < 268) v = f2b(state[r * 268 + c]);
    else if (c == 268) { float ang = t[0] * (2.f * 3.14159265358979323846f / 24.f); v = f2b(sinf(ang)); }
    else if (c == 269) { float ang = t[0] * (2.f * 3.14159265358979323846f / 24.f); v = f2b(cosf(ang)); }
    else v = 0;
    x_bf[i] = v;
  }
}

// out += 0.1*delta. cols<256: 0.1*(eh - state); cols 256..263: loc chain (fp32, exact)
__global__ void add_delta(float* __restrict__ out, const u16* __restrict__ eh,
                          const float* __restrict__ state,
                          const float* __restrict__ lp_in_w, const float* __restrict__ lp_in_b,
                          const float* __restrict__ lp_out_w, const float* __restrict__ lp_out_b,
                          const float* __restrict__ loc_proj_w, const float* __restrict__ loc_proj_b,
                          const float* __restrict__ loc_back_w, const float* __restrict__ loc_back_b)
{
  const int idx = blockIdx.x * 256 + threadIdx.x;
  if (idx >= 8192 * 268) return;
  const int row = idx / 268;
  const int col = idx - row * 268;
  if (col < 256) {
    out[idx] += 0.1f * (b2f(eh[row * 256 + col]) - state[idx]);
  } else if (col < 264) {
    const float* srow = state + row * 268 + 256;
    float locp[4], vv[4], dd[4];
#pragma unroll
    for (int e = 0; e < 4; e++) {
      float s = loc_proj_b[e];
#pragma unroll
      for (int z = 0; z < 8; z++) s += loc_proj_w[e * 8 + z] * srow[z];
      locp[e] = s;
    }
#pragma unroll
    for (int e = 0; e < 4; e++) {
      float s = lp_in_b[8 + e];
#pragma unroll
      for (int j = 0; j < 4; j++) s += lp_in_w[(8 + e) * 4 + j] * locp[j];
      vv[e] = s;
    }
#pragma unroll
    for (int e = 0; e < 4; e++) {
      float s = lp_out_b[e];
#pragma unroll
      for (int j = 0; j < 4; j++) s += lp_out_w[e * 4 + j] * vv[j];
      dd[e] = s - locp[e];
    }
    const int z = col - 256;
    float s = loc_back_b[z];
#pragma unroll
    for (int e = 0; e < 4; e++) s += loc_back_w[z * 4 + e] * dd[e];
    out[idx] += 0.1f * s;
  }
}

extern "C" void kernel_launch(void* const* d_in, const int* in_sizes, int n_in,
                              void* d_out, int out_size, void* d_ws, size_t ws_size,
                              hipStream_t stream)
{
  const float* t          = (const float*)d_in[0];
  const float* state      = (const float*)d_in[1];
  const float* W0         = (const float*)d_in[2];
  const float* b0         = (const float*)d_in[3];
  const float* rW1        = (const float*)d_in[4];
  const float* rb1        = (const float*)d_in[5];
  const float* rW2        = (const float*)d_in[6];
  const float* rb2        = (const float*)d_in[7];
  const float* Wf         = (const float*)d_in[8];
  const float* bfv        = (const float*)d_in[9];
  const float* lp_in_w    = (const float*)d_in[10];
  const float* lp_in_b    = (const float*)d_in[11];
  const float* lp_out_w   = (const float*)d_in[12];
  const float* lp_out_b   = (const float*)d_in[13];
  const float* ta_in_w    = (const float*)d_in[14];
  const float* ta_in_b    = (const float*)d_in[15];
  const float* ta_out_w   = (const float*)d_in[16];
  const float* ta_out_b   = (const float*)d_in[17];
  const float* loc_proj_w = (const float*)d_in[18];
  const float* loc_proj_b = (const float*)d_in[19];
  const float* loc_back_w = (const float*)d_in[20];
  const float* loc_back_b = (const float*)d_in[21];
  float* out = (float*)d_out;

  char* ws = (char*)d_ws;
  auto alloc = [&](size_t bytes) { char* p = ws; ws += (bytes + 255) & ~(size_t)255; return p; };
  u16* rw1_bf = (u16*)alloc((size_t)8 * 1024 * 1024 * 2);
  u16* rw2_bf = (u16*)alloc((size_t)8 * 1024 * 1024 * 2);
  u16* w0_bf  = (u16*)alloc((size_t)1024 * 288 * 2);
  u16* wf_bf  = (u16*)alloc((size_t)384 * 1024 * 2);
  u16* taA_bf = (u16*)alloc((size_t)256 * 256 * 2);
  u16* taB_bf = (u16*)alloc((size_t)256 * 256 * 2);
  u16* x_bf   = (u16*)alloc((size_t)8192 * 288 * 2);
  u16* h_bf   = (u16*)alloc((size_t)8192 * 1024 * 2);
  u16* tmp_bf = (u16*)alloc((size_t)8192 * 1024 * 2);
  u16* v2_bf  = (u16*)alloc((size_t)8192 * 256 * 2);
  u16* eh_bf  = (u16*)alloc((size_t)8192 * 256 * 2);

  // prep: fp32 -> bf16 conversions (+ padding, + time features)
  conv_bulk<<<16384, 256, 0, stream>>>(rW1, rW2, rw1_bf, rw2_bf);
  conv_misc<<<12416, 256, 0, stream>>>(W0, Wf, ta_in_w, ta_out_w, state, t,
                                       w0_bf, wf_bf, taA_bf, taB_bf, x_bf);

  // h = relu(x @ W0^T + b0)   (M=8192, N=1024, K=288 padded)
  gemm_bt<0><<<dim3(8, 64), 256, 0, stream>>>(x_bf, w0_bf, b0, nullptr, h_bf, 288, 288, 1024, 1024);

  // 8 residual blocks
  for (int r = 0; r < 8; r++) {
    gemm_bt<1><<<dim3(8, 64), 256, 0, stream>>>(h_bf, rw1_bf + (size_t)r * 1024 * 1024,
                                                rb1 + r * 1024, nullptr, tmp_bf, 1024, 1024, 1024, 1024);
    gemm_bt<2><<<dim3(8, 64), 256, 0, stream>>>(tmp_bf, rw2_bf + (size_t)r * 1024 * 1024,
                                                rb2 + r * 1024, h_bf, h_bf, 1024, 1024, 1024, 1024);
  }

  // ta path: v2 = h_part @ taW^T + b ; eh = v2 @ ta_out^T + b
  gemm_bt<4><<<dim3(2, 64), 256, 0, stream>>>(x_bf, taA_bf, ta_in_b + 512, nullptr, v2_bf, 256, 288, 256, 256);
  gemm_bt<4><<<dim3(2, 64), 256, 0, stream>>>(v2_bf, taB_bf, ta_out_b, nullptr, eh_bf, 256, 256, 256, 256);

  // core = h @ Wf^T + bf -> f32 out (N padded 268->384, store-predicated)
  gemm_bt<3><<<dim3(3, 64), 256, 0, stream>>>(h_bf, wf_bf, bfv, nullptr, out, 1024, 1024, 268, 268);

  // out += 0.1*delta
  add_delta<<<8576, 256, 0, stream>>>(out, eh_bf, state,
                                      lp_in_w, lp_in_b, lp_out_w, lp_out_b,
                                      loc_proj_w, loc_proj_b, loc_back_w, loc_back_b);
}

// Round 2
// 748.674 us; speedup vs baseline: 1.1411x; 1.1411x over previous
//
#include <hip/hip_runtime.h>
#include <hip/hip_bf16.h>

// OldODEFunc: B=8192, S=268, H=1024, R=8, A=256, E=4, Z=8, P=4.
// bf16 MFMA (16x16x32), fp32 accumulate.
// R1: 64x128 tile (1024 blocks -> 4/CU), BK=64 (half the barriers),
//     XOR-swizzled LDS (conflict-free ds_read_b128 under 128B row stride).

typedef unsigned short u16;
typedef __bf16 bf16x8 __attribute__((ext_vector_type(8)));
typedef float f32x4 __attribute__((ext_vector_type(4)));

__device__ __forceinline__ u16 f2b(float f) {
  union { float f; unsigned u; } v; v.f = f;
  unsigned r = v.u + 0x7FFFu + ((v.u >> 16) & 1u);   // RNE
  return (u16)(r >> 16);
}
__device__ __forceinline__ float b2f(u16 s) {
  union { unsigned u; float f; } v; v.u = ((unsigned)s) << 16;
  return v.f;
}

// async global->LDS, 16B per lane; lds dest = wave-uniform base + lane*16
__device__ __forceinline__ void g2l16(const u16* g, u16* l) {
  __builtin_amdgcn_global_load_lds(
      (__attribute__((address_space(1))) void*)g,
      (__attribute__((address_space(3))) void*)l, 16, 0, 0);
}

// C = A(M x K, row-major, stride lda) * B^T where B is (N x K) row-major (ldb == K).
// Tile: 64(M) x 128(N), BK=64. 4 waves in 2x2 (each 32x64). K, lda multiples of 64.
// LDS swizzle: 8-elem chunk c of row r stored at physical chunk c ^ (r&7).
// MODE 0: relu(acc+bias) -> bf16   MODE 1: tanh(acc+bias) -> bf16
// MODE 2: tanh(acc+bias+resid) -> bf16 (in-place-safe)
// MODE 3: acc+bias -> f32, cols<nreal   MODE 4: acc+bias -> bf16
template<int MODE>
__global__ __launch_bounds__(256, 4)
void gemm_bt(const u16* __restrict__ A, const u16* __restrict__ B,
             const float* __restrict__ bias, const u16* __restrict__ resid,
             void* __restrict__ outp, int K, int lda, int nreal, int ldo)
{
  __shared__ __align__(16) u16 As[64 * 64];    // 8 KB
  __shared__ __align__(16) u16 Bs[128 * 64];   // 16 KB
  const int tid  = threadIdx.x;
  const int wave = tid >> 6;
  const int lane = tid & 63;
  const int m0 = blockIdx.y << 6;
  const int n0 = blockIdx.x << 7;
  const int wr = wave >> 1, wc = wave & 1;       // 2x2 waves over 64x128
  const int lrow = lane & 15, quad = lane >> 4;  // MFMA fragment coords
  // staging: 8 lanes per 64-elem row, column permuted to realize the swizzle
  const int srow  = lane >> 3;                        // 0..7 within 8-row group
  const int sperm = ((lane & 7) ^ (srow & 7)) << 3;   // elems

  const u16* Ag0 = A + (size_t)(m0 + wave * 16 +  0 + srow) * lda + sperm;
  const u16* Ag1 = A + (size_t)(m0 + wave * 16 +  8 + srow) * lda + sperm;
  const u16* Bg0 = B + (size_t)(n0 + wave * 32 +  0 + srow) * K + sperm;
  const u16* Bg1 = B + (size_t)(n0 + wave * 32 +  8 + srow) * K + sperm;
  const u16* Bg2 = B + (size_t)(n0 + wave * 32 + 16 + srow) * K + sperm;
  const u16* Bg3 = B + (size_t)(n0 + wave * 32 + 24 + srow) * K + sperm;
  u16* Al0 = &As[(wave * 16 +  0) * 64];
  u16* Al1 = &As[(wave * 16 +  8) * 64];
  u16* Bl0 = &Bs[(wave * 32 +  0) * 64];
  u16* Bl1 = &Bs[(wave * 32 +  8) * 64];
  u16* Bl2 = &Bs[(wave * 32 + 16) * 64];
  u16* Bl3 = &Bs[(wave * 32 + 24) * 64];

  f32x4 acc[2][4];
#pragma unroll
  for (int i = 0; i < 2; i++)
#pragma unroll
    for (int j = 0; j < 4; j++) { f32x4 z = {0.f, 0.f, 0.f, 0.f}; acc[i][j] = z; }

  const int swz = lrow & 7;   // fragment-read swizzle key (row&7 == lrow&7 here)

  for (int k0 = 0; k0 < K; k0 += 64) {
    if (k0) __syncthreads();             // prior reads done before overwrite
    g2l16(Ag0 + k0, Al0);
    g2l16(Ag1 + k0, Al1);
    g2l16(Bg0 + k0, Bl0);
    g2l16(Bg1 + k0, Bl1);
    g2l16(Bg2 + k0, Bl2);
    g2l16(Bg3 + k0, Bl3);
    __syncthreads();                     // drains vmcnt: staging visible
#pragma unroll
    for (int s = 0; s < 2; s++) {
      const int c = (s * 4 + quad) ^ swz;   // physical chunk
      bf16x8 af[2], bfr[4];
#pragma unroll
      for (int i = 0; i < 2; i++) {
        const int ra = wr * 32 + i * 16 + lrow;
        af[i] = *reinterpret_cast<const bf16x8*>(&As[ra * 64 + c * 8]);
      }
#pragma unroll
      for (int j = 0; j < 4; j++) {
        const int rb = wc * 64 + j * 16 + lrow;
        bfr[j] = *reinterpret_cast<const bf16x8*>(&Bs[rb * 64 + c * 8]);
      }
#pragma unroll
      for (int i = 0; i < 2; i++)
#pragma unroll
        for (int j = 0; j < 4; j++)
          acc[i][j] = __builtin_amdgcn_mfma_f32_16x16x32_bf16(af[i], bfr[j], acc[i][j], 0, 0, 0);
    }
  }

  // epilogue: C/D layout col = lane&15, row = quad*4 + reg
#pragma unroll
  for (int i = 0; i < 2; i++) {
    const int rowb = m0 + wr * 32 + i * 16 + quad * 4;
#pragma unroll
    for (int j = 0; j < 4; j++) {
      const int col = n0 + wc * 64 + j * 16 + lrow;
      const float bi = (col < nreal) ? bias[col] : 0.f;
#pragma unroll
      for (int r = 0; r < 4; r++) {
        const int row = rowb + r;
        float v = acc[i][j][r] + bi;
        if (MODE == 0) {
          v = v > 0.f ? v : 0.f;
          ((u16*)outp)[(size_t)row * ldo + col] = f2b(v);
        } else if (MODE == 1) {
          ((u16*)outp)[(size_t)row * ldo + col] = f2b(tanhf(v));
        } else if (MODE == 2) {
          v += b2f(resid[(size_t)row * ldo + col]);
          ((u16*)outp)[(size_t)row * ldo + col] = f2b(tanhf(v));
        } else if (MODE == 3) {
          if (col < nreal) ((float*)outp)[(size_t)row * ldo + col] = v;
        } else {
          ((u16*)outp)[(size_t)row * ldo + col] = f2b(v);
        }
      }
    }
  }
}

// res_W1 + res_W2 (8M floats each) -> bf16, vectorized float4
__global__ void conv_bulk(const float* __restrict__ w1, const float* __restrict__ w2,
                          u16* __restrict__ o1, u16* __restrict__ o2)
{
  const int n4 = (8 * 1024 * 1024) / 4;  // 2097152 float4 per tensor
  int i = blockIdx.x * 256 + threadIdx.x;
  const float* src; u16* dst;
  if (i < n4) { src = w1; dst = o1; }
  else        { i -= n4; if (i >= n4) return; src = w2; dst = o2; }
  float4 v = ((const float4*)src)[i];
  unsigned p0 = (unsigned)f2b(v.x) | ((unsigned)f2b(v.y) << 16);
  unsigned p1 = (unsigned)f2b(v.z) | ((unsigned)f2b(v.w) << 16);
  uint2 pk; pk.x = p0; pk.y = p1;
  ((uint2*)dst)[i] = pk;
}

// W0 pad(1024x320), Wf pad(384x1024), taA(256x256), taB(256x256), x_bf(8192x320)
__global__ void conv_misc(const float* __restrict__ W0, const float* __restrict__ Wf,
                          const float* __restrict__ ta_in_w, const float* __restrict__ ta_out_w,
                          const float* __restrict__ state, const float* __restrict__ t,
                          u16* __restrict__ w0_bf, u16* __restrict__ wf_bf,
                          u16* __restrict__ taA, u16* __restrict__ taB,
                          u16* __restrict__ x_bf)
{
  int i = blockIdx.x * 256 + threadIdx.x;
  const int nW0 = 1024 * 320;
  const int nWf = 384 * 1024;
  const int nTa = 256 * 256;
  const int nX  = 8192 * 320;
  if (i < nW0) {
    int o = i / 320, k = i - o * 320;
    w0_bf[i] = (k < 270) ? f2b(W0[o * 270 + k]) : (u16)0;
    return;
  }
  i -= nW0;
  if (i < nWf) {
    int n = i >> 10;
    wf_bf[i] = (n < 268) ? f2b(Wf[i]) : (u16)0;
    return;
  }
  i -= nWf;
  if (i < nTa) { taA[i] = f2b(ta_in_w[512 * 256 + i]); return; }
  i -= nTa;
  if (i < nTa) { taB[i] = f2b(ta_out_w[i]); return; }
  i -= nTa;
  if (i < nX) {
    int r = i / 320, c = i - r * 320;
    u16 v;
    if (c < 268) v = f2b(state[r * 268 + c]);
    else if (c == 268) { float ang = t[0] * (2.f * 3.14159265358979323846f / 24.f); v = f2b(sinf(ang)); }
    else if (c == 269) { float ang = t[0] * (2.f * 3.14159265358979323846f / 24.f); v = f2b(cosf(ang)); }
    else v = 0;
    x_bf[i] = v;
  }
}

// out += 0.1*delta. cols<256: 0.1*(eh - state); cols 256..263: loc chain (fp32, exact)
__global__ void add_delta(float* __restrict__ out, const u16* __restrict__ eh,
                          const float* __restrict__ state,
                          const float* __restrict__ lp_in_w, const float* __restrict__ lp_in_b,
                          const float* __restrict__ lp_out_w, const float* __restrict__ lp_out_b,
                          const float* __restrict__ loc_proj_w, const float* __restrict__ loc_proj_b,
                          const float* __restrict__ loc_back_w, const float* __restrict__ loc_back_b)
{
  const int idx = blockIdx.x * 256 + threadIdx.x;
  if (idx >= 8192 * 268) return;
  const int row = idx / 268;
  const int col = idx - row * 268;
  if (col < 256) {
    out[idx] += 0.1f * (b2f(eh[row * 256 + col]) - state[idx]);
  } else if (col < 264) {
    const float* srow = state + row * 268 + 256;
    float locp[4], vv[4], dd[4];
#pragma unroll
    for (int e = 0; e < 4; e++) {
      float s = loc_proj_b[e];
#pragma unroll
      for (int z = 0; z < 8; z++) s += loc_proj_w[e * 8 + z] * srow[z];
      locp[e] = s;
    }
#pragma unroll
    for (int e = 0; e < 4; e++) {
      float s = lp_in_b[8 + e];
#pragma unroll
      for (int j = 0; j < 4; j++) s += lp_in_w[(8 + e) * 4 + j] * locp[j];
      vv[e] = s;
    }
#pragma unroll
    for (int e = 0; e < 4; e++) {
      float s = lp_out_b[e];
#pragma unroll
      for (int j = 0; j < 4; j++) s += lp_out_w[e * 4 + j] * vv[j];
      dd[e] = s - locp[e];
    }
    const int z = col - 256;
    float s = loc_back_b[z];
#pragma unroll
    for (int e = 0; e < 4; e++) s += loc_back_w[z * 4 + e] * dd[e];
    out[idx] += 0.1f * s;
  }
}

extern "C" void kernel_launch(void* const* d_in, const int* in_sizes, int n_in,
                              void* d_out, int out_size, void* d_ws, size_t ws_size,
                              hipStream_t stream)
{
  const float* t          = (const float*)d_in[0];
  const float* state      = (const float*)d_in[1];
  const float* W0         = (const float*)d_in[2];
  const float* b0         = (const float*)d_in[3];
  const float* rW1        = (const float*)d_in[4];
  const float* rb1        = (const float*)d_in[5];
  const float* rW2        = (const float*)d_in[6];
  const float* rb2        = (const float*)d_in[7];
  const float* Wf         = (const float*)d_in[8];
  const float* bfv        = (const float*)d_in[9];
  const float* lp_in_w    = (const float*)d_in[10];
  const float* lp_in_b    = (const float*)d_in[11];
  const float* lp_out_w   = (const float*)d_in[12];
  const float* lp_out_b   = (const float*)d_in[13];
  const float* ta_in_w    = (const float*)d_in[14];
  const float* ta_in_b    = (const float*)d_in[15];
  const float* ta_out_w   = (const float*)d_in[16];
  const float* ta_out_b   = (const float*)d_in[17];
  const float* loc_proj_w = (const float*)d_in[18];
  const float* loc_proj_b = (const float*)d_in[19];
  const float* loc_back_w = (const float*)d_in[20];
  const float* loc_back_b = (const float*)d_in[21];
  float* out = (float*)d_out;

  char* ws = (char*)d_ws;
  auto alloc = [&](size_t bytes) { char* p = ws; ws += (bytes + 255) & ~(size_t)255; return p; };
  u16* rw1_bf = (u16*)alloc((size_t)8 * 1024 * 1024 * 2);
  u16* rw2_bf = (u16*)alloc((size_t)8 * 1024 * 1024 * 2);
  u16* w0_bf  = (u16*)alloc((size_t)1024 * 320 * 2);
  u16* wf_bf  = (u16*)alloc((size_t)384 * 1024 * 2);
  u16* taA_bf = (u16*)alloc((size_t)256 * 256 * 2);
  u16* taB_bf = (u16*)alloc((size_t)256 * 256 * 2);
  u16* x_bf   = (u16*)alloc((size_t)8192 * 320 * 2);
  u16* h_bf   = (u16*)alloc((size_t)8192 * 1024 * 2);
  u16* tmp_bf = (u16*)alloc((size_t)8192 * 1024 * 2);
  u16* v2_bf  = (u16*)alloc((size_t)8192 * 256 * 2);
  u16* eh_bf  = (u16*)alloc((size_t)8192 * 256 * 2);

  // prep: fp32 -> bf16 conversions (+ padding, + time features)
  conv_bulk<<<16384, 256, 0, stream>>>(rW1, rW2, rw1_bf, rw2_bf);
  conv_misc<<<13568, 256, 0, stream>>>(W0, Wf, ta_in_w, ta_out_w, state, t,
                                       w0_bf, wf_bf, taA_bf, taB_bf, x_bf);

  // h = relu(x @ W0^T + b0)   (M=8192, N=1024, K=270 padded to 320)
  gemm_bt<0><<<dim3(8, 128), 256, 0, stream>>>(x_bf, w0_bf, b0, nullptr, h_bf, 320, 320, 1024, 1024);

  // 8 residual blocks
  for (int r = 0; r < 8; r++) {
    gemm_bt<1><<<dim3(8, 128), 256, 0, stream>>>(h_bf, rw1_bf + (size_t)r * 1024 * 1024,
                                                 rb1 + r * 1024, nullptr, tmp_bf, 1024, 1024, 1024, 1024);
    gemm_bt<2><<<dim3(8, 128), 256, 0, stream>>>(tmp_bf, rw2_bf + (size_t)r * 1024 * 1024,
                                                 rb2 + r * 1024, h_bf, h_bf, 1024, 1024, 1024, 1024);
  }

  // ta path: v2 = h_part @ taW^T + b ; eh = v2 @ ta_out^T + b
  gemm_bt<4><<<dim3(2, 128), 256, 0, stream>>>(x_bf, taA_bf, ta_in_b + 512, nullptr, v2_bf, 256, 320, 256, 256);
  gemm_bt<4><<<dim3(2, 128), 256, 0, stream>>>(v2_bf, taB_bf, ta_out_b, nullptr, eh_bf, 256, 256, 256, 256);

  // core = h @ Wf^T + bf -> f32 out (N padded 268->384, store-predicated)
  gemm_bt<3><<<dim3(3, 128), 256, 0, stream>>>(h_bf, wf_bf, bfv, nullptr, out, 1024, 1024, 268, 268);

  // out += 0.1*delta
  add_delta<<<8576, 256, 0, stream>>>(out, eh_bf, state,
                                      lp_in_w, lp_in_b, lp_out_w, lp_out_b,
                                      loc_proj_w, loc_proj_b, loc_back_w, loc_back_b);
}